// Round 4
// baseline (1195.302 us; speedup 1.0000x reference)
//
#include <hip/hip_runtime.h>

// FlashMultiHeadAttention  B=4 S=2048 HIDDEN=1024 H=16 Dh=64 (fp32 I/O)
// r4: flash attn with coalesced epilogue, bf16 pre-scaled rel, K/V reg-prefetch,
//     128-thread blocks (4 blocks/CU). Q pre-scaled by 0.125*log2e in qkv_proj.
// ws (u16 elems): Qw[0,8M) Kw[8M,16M) Vt[16M,24M) Ow[24M,32M) rel'[32M,48M) = 96 MB.

#define SEQ 2048
#define NH 16
#define DH 64
#define HID 1024
#define QSCALE 0.18033688011112f   // 0.125 * log2(e)

typedef short bf16x8 __attribute__((ext_vector_type(8)));
typedef float f32x4  __attribute__((ext_vector_type(4)));
typedef unsigned short u16;
typedef unsigned short u16x4 __attribute__((ext_vector_type(4)));

__device__ __forceinline__ float b2f(u16 u) {
    union { unsigned i; float f; } x; x.i = ((unsigned)u) << 16; return x.f;
}
__device__ __forceinline__ u16 f2b(float f) {
    union { float f; unsigned i; } x; x.f = f;
    unsigned r = x.i + 0x7fffu + ((x.i >> 16) & 1u);
    return (u16)(r >> 16);
}
__device__ __forceinline__ bf16x8 cvt8(const float* p) {
    f32x4 x0 = *(const f32x4*)p;
    f32x4 x1 = *(const f32x4*)(p + 4);
    bf16x8 r;
#pragma unroll
    for (int j = 0; j < 4; ++j) { r[j] = (short)f2b(x0[j]); r[j + 4] = (short)f2b(x1[j]); }
    return r;
}

// ---------------- rel -> bf16, pre-scaled into exp2 domain ----------------
__global__ __launch_bounds__(256) void rel_cvt_kernel(
    const float* __restrict__ rel, u16* __restrict__ out)
{
    const size_t i0 = ((size_t)blockIdx.x * 256 + threadIdx.x) * 4;
#pragma unroll
    for (int it = 0; it < 16; ++it) {
        const size_t i = i0 + (size_t)it * 1048576;   // 262144 threads * 4
        f32x4 x = *(const f32x4*)(rel + i);
        u16x4 o;
#pragma unroll
        for (int j = 0; j < 4; ++j) o[j] = f2b(x[j] * QSCALE);
        *(u16x4*)(out + i) = o;
    }
}

// ---------------- QKV projection: bf16 MFMA, Y = X @ W^T + b (Q pre-scaled) ----------------
__global__ __launch_bounds__(256) void qkv_proj_kernel(
    const float* __restrict__ xq, const float* __restrict__ xk, const float* __restrict__ xv,
    const float* __restrict__ wq, const float* __restrict__ bq,
    const float* __restrict__ wk, const float* __restrict__ bk,
    const float* __restrict__ wv, const float* __restrict__ bv,
    u16* __restrict__ Qw, u16* __restrict__ Kw, u16* __restrict__ Vw)
{
    const int wid  = (blockIdx.x << 2) | (threadIdx.x >> 6);
    const int lane = threadIdx.x & 63;
    const int tm = wid / 48;
    const int tn = wid % 48;
    const int sel = tn >> 4;            // 0=q 1=k 2=v
    const int n0 = (tn & 15) << 6;
    const int m0 = tm << 6;

    const float* X    = sel == 0 ? xq : (sel == 1 ? xk : xv);
    const float* W    = sel == 0 ? wq : (sel == 1 ? wk : wv);
    const float* bias = sel == 0 ? bq : (sel == 1 ? bk : bv);

    const int quad = lane >> 4;
    const int l16  = lane & 15;

    f32x4 acc[4][4];
    const f32x4 zero = {0.f, 0.f, 0.f, 0.f};
#pragma unroll
    for (int r = 0; r < 4; ++r)
#pragma unroll
        for (int c = 0; c < 4; ++c) acc[r][c] = zero;

    const float* ar[4]; const float* br[4];
#pragma unroll
    for (int r = 0; r < 4; ++r) ar[r] = X + (size_t)(m0 + r * 16 + l16) * 1024 + quad * 8;
#pragma unroll
    for (int c = 0; c < 4; ++c) br[c] = W + (size_t)(n0 + c * 16 + l16) * 1024 + quad * 8;

    for (int k0 = 0; k0 < 1024; k0 += 32) {
        bf16x8 a[4], b[4];
#pragma unroll
        for (int r = 0; r < 4; ++r) a[r] = cvt8(ar[r] + k0);
#pragma unroll
        for (int c = 0; c < 4; ++c) b[c] = cvt8(br[c] + k0);
#pragma unroll
        for (int r = 0; r < 4; ++r)
#pragma unroll
            for (int c = 0; c < 4; ++c)
                acc[r][c] = __builtin_amdgcn_mfma_f32_16x16x32_bf16(a[r], b[c], acc[r][c], 0, 0, 0);
    }

    // C layout: col(n)=lane&15, row(m)=quad*4+reg
#pragma unroll
    for (int c = 0; c < 4; ++c) {
        const int n = n0 + c * 16 + l16;
        const float bn = bias[n];
        const int h = n >> 6, d = n & 63;
#pragma unroll
        for (int r = 0; r < 4; ++r) {
#pragma unroll
            for (int g = 0; g < 4; ++g) {
                const int m  = m0 + r * 16 + quad * 4 + g;
                const int b_ = m >> 11, s_ = m & 2047;
                const float val = acc[r][c][g] + bn;
                if (sel == 0)
                    Qw[(((size_t)(b_ * 16 + h)) * 2048 + s_) * 64 + d] = f2b(val * QSCALE);
                else if (sel == 1)
                    Kw[(((size_t)(b_ * 16 + h)) * 2048 + s_) * 64 + d] = f2b(val);
                else
                    Vw[(((size_t)(b_ * 16 + h)) * 64 + d) * 2048 + s_] = f2b(val);  // transposed
            }
        }
    }
}

// ---------------- Flash attention: 2 waves/block, 64 q per wave ----------------
// LDS pad 80 u16 (160 B rows): all b128 read patterns are <=2-way (free).
__global__ __launch_bounds__(128, 2) void attn_kernel(
    const u16* __restrict__ Qb, const u16* __restrict__ Kb,
    const u16* __restrict__ Vb, const u16* __restrict__ relb,
    u16* __restrict__ Ob)
{
    __shared__ __align__(16) u16 lds[20480];   // K 64x80 | V 64x80 | Pl0 | Pl1 (40960 B)
    u16* Ks = lds;
    u16* Vt = lds + 5120;

    const int tid  = threadIdx.x;
    const int w    = tid >> 6;
    const int lane = tid & 63;
    const int l16  = lane & 15;
    const int quad = lane >> 4;
    u16* Pl = lds + 10240 + w * 5120;

    const int bh = blockIdx.x & 63;
    const int i  = blockIdx.x >> 6;              // 16 strips of 128 queries
    const int qb = (i < 8) ? i : (23 - i);       // pair strip j with 15-j for balance
    const int b  = bh >> 4, h = bh & 15;
    const int q0w = qb * 128 + w * 64;

    // Q A-fragments (persistent; Q already scaled by QSCALE)
    bf16x8 qa[4][2];
    const u16* Qp = Qb + (size_t)bh * SEQ * DH;
#pragma unroll
    for (int mt = 0; mt < 4; ++mt)
#pragma unroll
        for (int ks = 0; ks < 2; ++ks)
            qa[mt][ks] = *(const bf16x8*)(Qp + (size_t)(q0w + mt * 16 + l16) * 64 + ks * 32 + quad * 8);

    f32x4 o[4][4], mrow[4], lrow[4];
    const f32x4 zero = {0.f, 0.f, 0.f, 0.f};
    const f32x4 ninf = {-1e30f, -1e30f, -1e30f, -1e30f};
#pragma unroll
    for (int mt = 0; mt < 4; ++mt) {
        mrow[mt] = ninf; lrow[mt] = zero;
#pragma unroll
        for (int dt = 0; dt < 4; ++dt) o[mt][dt] = zero;
    }

    const u16* relB = relb + (size_t)b * SEQ * SEQ;
    const u16* Kg = Kb + (size_t)bh * SEQ * DH;
    const u16* Vg = Vb + (size_t)bh * DH * SEQ;

    const int ntiles  = qb * 2 + 2;
    const int mytiles = qb * 2 + w + 1;

    // prefetch tile 0 into regs
    bf16x8 kreg[4], vreg[4];
#pragma unroll
    for (int p = 0; p < 4; ++p) {
        const int c = tid + p * 128;
        const int row = c >> 3, c8 = (c & 7) << 3;
        kreg[p] = *(const bf16x8*)(Kg + (size_t)row * 64 + c8);
        vreg[p] = *(const bf16x8*)(Vg + (size_t)row * 2048 + c8);
    }

    for (int kt = 0; kt < ntiles; ++kt) {
        const int k0 = kt << 6;
        // regs -> LDS; then issue next tile's global loads (latency hidden under compute)
#pragma unroll
        for (int p = 0; p < 4; ++p) {
            const int c = tid + p * 128;
            const int row = c >> 3, c8 = (c & 7) << 3;
            *(bf16x8*)(Ks + row * 80 + c8) = kreg[p];
            *(bf16x8*)(Vt + row * 80 + c8) = vreg[p];
        }
        const int kn = (kt + 1 < ntiles ? kt + 1 : kt) << 6;
#pragma unroll
        for (int p = 0; p < 4; ++p) {
            const int c = tid + p * 128;
            const int row = c >> 3, c8 = (c & 7) << 3;
            kreg[p] = *(const bf16x8*)(Kg + (size_t)(kn + row) * 64 + c8);
            vreg[p] = *(const bf16x8*)(Vg + (size_t)row * 2048 + kn + c8);
        }
        __syncthreads();

        if (kt < mytiles) {
            // ---- scores: C init = rel' (bf16, pre-scaled), MFMA adds scaled QK^T ----
            f32x4 s[4][4];
#pragma unroll
            for (int mt = 0; mt < 4; ++mt)
#pragma unroll
                for (int nt = 0; nt < 4; ++nt)
#pragma unroll
                    for (int g = 0; g < 4; ++g)
                        s[mt][nt][g] = b2f(relB[(size_t)(q0w + mt * 16 + quad * 4 + g) * SEQ
                                                + k0 + nt * 16 + l16]);
#pragma unroll
            for (int nt = 0; nt < 4; ++nt) {
                bf16x8 kb0 = *(const bf16x8*)(Ks + (nt * 16 + l16) * 80 + quad * 8);
                bf16x8 kb1 = *(const bf16x8*)(Ks + (nt * 16 + l16) * 80 + 32 + quad * 8);
#pragma unroll
                for (int mt = 0; mt < 4; ++mt) {
                    s[mt][nt] = __builtin_amdgcn_mfma_f32_16x16x32_bf16(qa[mt][0], kb0, s[mt][nt], 0, 0, 0);
                    s[mt][nt] = __builtin_amdgcn_mfma_f32_16x16x32_bf16(qa[mt][1], kb1, s[mt][nt], 0, 0, 0);
                }
            }
            // ---- causal mask (diagonal tile only; scores already in exp2 domain) ----
            if (kt == mytiles - 1) {
#pragma unroll
                for (int mt = 0; mt < 4; ++mt)
#pragma unroll
                    for (int nt = 0; nt < 4; ++nt)
#pragma unroll
                        for (int g = 0; g < 4; ++g) {
                            const int q = q0w + mt * 16 + quad * 4 + g;
                            const int k = k0 + nt * 16 + l16;
                            if (k > q) s[mt][nt][g] = -1e30f;
                        }
            }
            // ---- online softmax (exp2 domain) ----
#pragma unroll
            for (int mt = 0; mt < 4; ++mt) {
                f32x4 t;
#pragma unroll
                for (int g = 0; g < 4; ++g)
                    t[g] = fmaxf(fmaxf(s[mt][0][g], s[mt][1][g]), fmaxf(s[mt][2][g], s[mt][3][g]));
#pragma unroll
                for (int off = 1; off < 16; off <<= 1)
#pragma unroll
                    for (int g = 0; g < 4; ++g)
                        t[g] = fmaxf(t[g], __shfl_xor(t[g], off, 64));
                f32x4 mn, alpha;
#pragma unroll
                for (int g = 0; g < 4; ++g) {
                    mn[g] = fmaxf(mrow[mt][g], t[g]);
                    alpha[g] = __builtin_amdgcn_exp2f(mrow[mt][g] - mn[g]);
                }
                mrow[mt] = mn;
#pragma unroll
                for (int g = 0; g < 4; ++g) lrow[mt][g] *= alpha[g];
#pragma unroll
                for (int dt = 0; dt < 4; ++dt)
#pragma unroll
                    for (int g = 0; g < 4; ++g) o[mt][dt][g] *= alpha[g];
#pragma unroll
                for (int nt = 0; nt < 4; ++nt)
#pragma unroll
                    for (int g = 0; g < 4; ++g)
                        s[mt][nt][g] = __builtin_amdgcn_exp2f(s[mt][nt][g] - mn[g]);
                f32x4 rs;
#pragma unroll
                for (int g = 0; g < 4; ++g)
                    rs[g] = (s[mt][0][g] + s[mt][1][g]) + (s[mt][2][g] + s[mt][3][g]);
#pragma unroll
                for (int off = 1; off < 16; off <<= 1)
#pragma unroll
                    for (int g = 0; g < 4; ++g)
                        rs[g] += __shfl_xor(rs[g], off, 64);
#pragma unroll
                for (int g = 0; g < 4; ++g) lrow[mt][g] += rs[g];
            }
            // ---- P -> bf16 -> per-wave LDS ----
#pragma unroll
            for (int mt = 0; mt < 4; ++mt)
#pragma unroll
                for (int nt = 0; nt < 4; ++nt)
#pragma unroll
                    for (int g = 0; g < 4; ++g)
                        Pl[(mt * 16 + quad * 4 + g) * 80 + nt * 16 + l16] = f2b(s[mt][nt][g]);
            // ---- PV ----
            bf16x8 pa[4][2];
#pragma unroll
            for (int mt = 0; mt < 4; ++mt)
#pragma unroll
                for (int ks = 0; ks < 2; ++ks)
                    pa[mt][ks] = *(const bf16x8*)(Pl + (mt * 16 + l16) * 80 + ks * 32 + quad * 8);
#pragma unroll
            for (int dt = 0; dt < 4; ++dt) {
                bf16x8 vb0 = *(const bf16x8*)(Vt + (dt * 16 + l16) * 80 + quad * 8);
                bf16x8 vb1 = *(const bf16x8*)(Vt + (dt * 16 + l16) * 80 + 32 + quad * 8);
#pragma unroll
                for (int mt = 0; mt < 4; ++mt) {
                    o[mt][dt] = __builtin_amdgcn_mfma_f32_16x16x32_bf16(pa[mt][0], vb0, o[mt][dt], 0, 0, 0);
                    o[mt][dt] = __builtin_amdgcn_mfma_f32_16x16x32_bf16(pa[mt][1], vb1, o[mt][dt], 0, 0, 0);
                }
            }
        }
        __syncthreads();
    }

    // ---- epilogue: O/l -> per-wave LDS -> coalesced 64B-segment stores ----
#pragma unroll
    for (int mt = 0; mt < 4; ++mt) {
        f32x4 linv;
#pragma unroll
        for (int g = 0; g < 4; ++g) linv[g] = 1.0f / lrow[mt][g];
#pragma unroll
        for (int dt = 0; dt < 4; ++dt)
#pragma unroll
            for (int g = 0; g < 4; ++g)
                Pl[(mt * 16 + quad * 4 + g) * 80 + dt * 16 + l16] = f2b(o[mt][dt][g] * linv[g]);
    }
    const int c4 = lane & 3, rr = lane >> 2;
#pragma unroll
    for (int p = 0; p < 4; ++p) {
        const int r = p * 16 + rr;
        bf16x8 t0 = *(const bf16x8*)(Pl + r * 80 + c4 * 8);
        bf16x8 t1 = *(const bf16x8*)(Pl + r * 80 + 32 + c4 * 8);
        u16* dst = Ob + ((size_t)b * SEQ + q0w + r) * HID + h * DH;
        *(bf16x8*)(dst + c4 * 8) = t0;
        *(bf16x8*)(dst + 32 + c4 * 8) = t1;
    }
}

// ---------------- Output projection: out = O @ Wout^T + bout (fp32 out) ----------------
__global__ __launch_bounds__(256) void out_proj_kernel(
    const u16* __restrict__ X, const float* __restrict__ W,
    const float* __restrict__ bias, float* __restrict__ out)
{
    const int wid  = (blockIdx.x << 2) | (threadIdx.x >> 6);
    const int lane = threadIdx.x & 63;
    const int tm = wid >> 4;
    const int tn = wid & 15;
    const int n0 = tn << 6;
    const int m0 = tm << 6;

    const int quad = lane >> 4;
    const int l16  = lane & 15;

    f32x4 acc[4][4];
    const f32x4 zero = {0.f, 0.f, 0.f, 0.f};
#pragma unroll
    for (int r = 0; r < 4; ++r)
#pragma unroll
        for (int c = 0; c < 4; ++c) acc[r][c] = zero;

    const u16* ar[4]; const float* br[4];
#pragma unroll
    for (int r = 0; r < 4; ++r) ar[r] = X + (size_t)(m0 + r * 16 + l16) * 1024 + quad * 8;
#pragma unroll
    for (int c = 0; c < 4; ++c) br[c] = W + (size_t)(n0 + c * 16 + l16) * 1024 + quad * 8;

    for (int k0 = 0; k0 < 1024; k0 += 32) {
        bf16x8 a[4], b[4];
#pragma unroll
        for (int r = 0; r < 4; ++r) a[r] = *(const bf16x8*)(ar[r] + k0);
#pragma unroll
        for (int c = 0; c < 4; ++c) b[c] = cvt8(br[c] + k0);
#pragma unroll
        for (int r = 0; r < 4; ++r)
#pragma unroll
            for (int c = 0; c < 4; ++c)
                acc[r][c] = __builtin_amdgcn_mfma_f32_16x16x32_bf16(a[r], b[c], acc[r][c], 0, 0, 0);
    }

#pragma unroll
    for (int c = 0; c < 4; ++c) {
        const int n = n0 + c * 16 + l16;
        const float bn = bias[n];
#pragma unroll
        for (int r = 0; r < 4; ++r) {
#pragma unroll
            for (int g = 0; g < 4; ++g) {
                const int m = m0 + r * 16 + quad * 4 + g;
                out[(size_t)m * 1024 + n] = acc[r][c][g] + bn;
            }
        }
    }
}

extern "C" void kernel_launch(void* const* d_in, const int* in_sizes, int n_in,
                              void* d_out, int out_size, void* d_ws, size_t ws_size,
                              hipStream_t stream)
{
    const float* q   = (const float*)d_in[0];
    const float* k   = (const float*)d_in[1];
    const float* v   = (const float*)d_in[2];
    const float* rel = (const float*)d_in[3];
    // d_in[4] = attn_mask: statically causal tril, not read
    const float* wq = (const float*)d_in[5];  const float* bq = (const float*)d_in[6];
    const float* wk = (const float*)d_in[7];  const float* bk = (const float*)d_in[8];
    const float* wv = (const float*)d_in[9];  const float* bv = (const float*)d_in[10];
    const float* wo = (const float*)d_in[11]; const float* bo = (const float*)d_in[12];

    u16* ws = (u16*)d_ws;                 // 96 MB used
    u16* Qw   = ws;
    u16* Kw   = ws + 8388608ULL;
    u16* Vw   = ws + 16777216ULL;
    u16* Ow   = ws + 25165824ULL;
    u16* relb = ws + 33554432ULL;

    rel_cvt_kernel<<<1024, 256, 0, stream>>>(rel, relb);
    qkv_proj_kernel<<<1536, 256, 0, stream>>>(q, k, v, wq, bq, wk, bk, wv, bv, Qw, Kw, Vw);
    attn_kernel<<<1024, 128, 0, stream>>>(Qw, Kw, Vw, relb, Ow);
    out_proj_kernel<<<512, 256, 0, stream>>>(Ow, wo, bo, (float*)d_out);
}

// Round 5
// 766.898 us; speedup vs baseline: 1.5586x; 1.5586x over previous
//
#include <hip/hip_runtime.h>

// FlashMultiHeadAttention  B=4 S=2048 HIDDEN=1024 H=16 Dh=64 (fp32 I/O)
// r5: spill fix — 32 queries/wave (4 waves/block). r4's 64q/wave needed ~224 live
//     VGPRs vs 128 allocated -> scratch spills = the 175MB WRITE_SIZE / 10x latency.
// ws (u16 elems): Qw[0,8M) Kw[8M,16M) Vt[16M,24M) Ow[24M,32M) rel'[32M,48M) = 96 MB.

#define SEQ 2048
#define NH 16
#define DH 64
#define HID 1024
#define QSCALE 0.18033688011112f   // 0.125 * log2(e)

typedef short bf16x8 __attribute__((ext_vector_type(8)));
typedef float f32x4  __attribute__((ext_vector_type(4)));
typedef unsigned short u16;
typedef unsigned short u16x4 __attribute__((ext_vector_type(4)));

__device__ __forceinline__ float b2f(u16 u) {
    union { unsigned i; float f; } x; x.i = ((unsigned)u) << 16; return x.f;
}
__device__ __forceinline__ u16 f2b(float f) {
    union { float f; unsigned i; } x; x.f = f;
    unsigned r = x.i + 0x7fffu + ((x.i >> 16) & 1u);
    return (u16)(r >> 16);
}
__device__ __forceinline__ bf16x8 cvt8(const float* p) {
    f32x4 x0 = *(const f32x4*)p;
    f32x4 x1 = *(const f32x4*)(p + 4);
    bf16x8 r;
#pragma unroll
    for (int j = 0; j < 4; ++j) { r[j] = (short)f2b(x0[j]); r[j + 4] = (short)f2b(x1[j]); }
    return r;
}

// ---------------- rel -> bf16, pre-scaled into exp2 domain ----------------
__global__ __launch_bounds__(256) void rel_cvt_kernel(
    const float* __restrict__ rel, u16* __restrict__ out)
{
    const size_t i0 = ((size_t)blockIdx.x * 256 + threadIdx.x) * 4;
#pragma unroll
    for (int it = 0; it < 16; ++it) {
        const size_t i = i0 + (size_t)it * 1048576;
        f32x4 x = *(const f32x4*)(rel + i);
        u16x4 o;
#pragma unroll
        for (int j = 0; j < 4; ++j) o[j] = f2b(x[j] * QSCALE);
        *(u16x4*)(out + i) = o;
    }
}

// ---------------- QKV projection: bf16 MFMA, Y = X @ W^T + b (Q pre-scaled) ----------------
__global__ __launch_bounds__(256) void qkv_proj_kernel(
    const float* __restrict__ xq, const float* __restrict__ xk, const float* __restrict__ xv,
    const float* __restrict__ wq, const float* __restrict__ bq,
    const float* __restrict__ wk, const float* __restrict__ bk,
    const float* __restrict__ wv, const float* __restrict__ bv,
    u16* __restrict__ Qw, u16* __restrict__ Kw, u16* __restrict__ Vw)
{
    const int wid  = (blockIdx.x << 2) | (threadIdx.x >> 6);
    const int lane = threadIdx.x & 63;
    const int tm = wid / 48;
    const int tn = wid % 48;
    const int sel = tn >> 4;            // 0=q 1=k 2=v
    const int n0 = (tn & 15) << 6;
    const int m0 = tm << 6;

    const float* X    = sel == 0 ? xq : (sel == 1 ? xk : xv);
    const float* W    = sel == 0 ? wq : (sel == 1 ? wk : wv);
    const float* bias = sel == 0 ? bq : (sel == 1 ? bk : bv);

    const int quad = lane >> 4;
    const int l16  = lane & 15;

    f32x4 acc[4][4];
    const f32x4 zero = {0.f, 0.f, 0.f, 0.f};
#pragma unroll
    for (int r = 0; r < 4; ++r)
#pragma unroll
        for (int c = 0; c < 4; ++c) acc[r][c] = zero;

    const float* ar[4]; const float* br[4];
#pragma unroll
    for (int r = 0; r < 4; ++r) ar[r] = X + (size_t)(m0 + r * 16 + l16) * 1024 + quad * 8;
#pragma unroll
    for (int c = 0; c < 4; ++c) br[c] = W + (size_t)(n0 + c * 16 + l16) * 1024 + quad * 8;

    for (int k0 = 0; k0 < 1024; k0 += 32) {
        bf16x8 a[4], b[4];
#pragma unroll
        for (int r = 0; r < 4; ++r) a[r] = cvt8(ar[r] + k0);
#pragma unroll
        for (int c = 0; c < 4; ++c) b[c] = cvt8(br[c] + k0);
#pragma unroll
        for (int r = 0; r < 4; ++r)
#pragma unroll
            for (int c = 0; c < 4; ++c)
                acc[r][c] = __builtin_amdgcn_mfma_f32_16x16x32_bf16(a[r], b[c], acc[r][c], 0, 0, 0);
    }

    // C layout: col(n)=lane&15, row(m)=quad*4+reg
#pragma unroll
    for (int c = 0; c < 4; ++c) {
        const int n = n0 + c * 16 + l16;
        const float bn = bias[n];
        const int h = n >> 6, d = n & 63;
#pragma unroll
        for (int r = 0; r < 4; ++r) {
#pragma unroll
            for (int g = 0; g < 4; ++g) {
                const int m  = m0 + r * 16 + quad * 4 + g;
                const int b_ = m >> 11, s_ = m & 2047;
                const float val = acc[r][c][g] + bn;
                if (sel == 0)
                    Qw[(((size_t)(b_ * 16 + h)) * 2048 + s_) * 64 + d] = f2b(val * QSCALE);
                else if (sel == 1)
                    Kw[(((size_t)(b_ * 16 + h)) * 2048 + s_) * 64 + d] = f2b(val);
                else
                    Vw[(((size_t)(b_ * 16 + h)) * 64 + d) * 2048 + s_] = f2b(val);  // transposed
            }
        }
    }
}

// ---------------- Flash attention: 4 waves/block, 32 q per wave ----------------
__global__ __launch_bounds__(256, 2) void attn_kernel(
    const u16* __restrict__ Qb, const u16* __restrict__ Kb,
    const u16* __restrict__ Vb, const u16* __restrict__ relb,
    u16* __restrict__ Ob)
{
    __shared__ __align__(16) u16 lds[18432];   // Ks 64x72 | Vt 64x72 | Pl 4x(32x72) = 36864 B
    u16* Ks = lds;
    u16* Vt = lds + 4608;

    const int tid  = threadIdx.x;
    const int w    = tid >> 6;
    const int lane = tid & 63;
    const int l16  = lane & 15;
    const int quad = lane >> 4;
    u16* Pl = lds + 9216 + w * 2304;

    const int bh = blockIdx.x & 63;
    const int i  = blockIdx.x >> 6;              // 16 strips of 128 queries
    const int qb = (i < 8) ? i : (23 - i);       // pair strip j with 15-j for balance
    const int b  = bh >> 4, h = bh & 15;
    const int q0w = qb * 128 + w * 32;           // wave's 32-query window

    // Q A-fragments (persistent; Q pre-scaled by QSCALE)
    bf16x8 qa[2][2];
    const u16* Qp = Qb + (size_t)bh * SEQ * DH;
#pragma unroll
    for (int mt = 0; mt < 2; ++mt)
#pragma unroll
        for (int ks = 0; ks < 2; ++ks)
            qa[mt][ks] = *(const bf16x8*)(Qp + (size_t)(q0w + mt * 16 + l16) * 64 + ks * 32 + quad * 8);

    f32x4 o[2][4], mrow[2], lrow[2];
    const f32x4 zero = {0.f, 0.f, 0.f, 0.f};
    const f32x4 ninf = {-1e30f, -1e30f, -1e30f, -1e30f};
#pragma unroll
    for (int mt = 0; mt < 2; ++mt) {
        mrow[mt] = ninf; lrow[mt] = zero;
#pragma unroll
        for (int dt = 0; dt < 4; ++dt) o[mt][dt] = zero;
    }

    const u16* relB = relb + (size_t)b * SEQ * SEQ;
    const u16* Kg = Kb + (size_t)bh * SEQ * DH;
    const u16* Vg = Vb + (size_t)bh * DH * SEQ;

    const int ntiles  = qb * 2 + 2;              // staged by the block
    const int mytiles = qb * 2 + (w >> 1) + 1;   // processed by this wave

    // staging indices: 512 16B-chunks per tile pair-kind, 2 per thread
    const int c0 = tid, c1 = tid + 256;
    const int r0 = c0 >> 3, o0 = (c0 & 7) << 3;
    const int r1 = c1 >> 3, o1 = (c1 & 7) << 3;

    // prefetch tile 0
    bf16x8 kreg0 = *(const bf16x8*)(Kg + (size_t)r0 * 64 + o0);
    bf16x8 kreg1 = *(const bf16x8*)(Kg + (size_t)r1 * 64 + o1);
    bf16x8 vreg0 = *(const bf16x8*)(Vg + (size_t)r0 * 2048 + o0);
    bf16x8 vreg1 = *(const bf16x8*)(Vg + (size_t)r1 * 2048 + o1);

    for (int kt = 0; kt < ntiles; ++kt) {
        const int k0 = kt << 6;
        // regs -> LDS, then issue next tile's loads (latency hidden under compute)
        *(bf16x8*)(Ks + r0 * 72 + o0) = kreg0;
        *(bf16x8*)(Ks + r1 * 72 + o1) = kreg1;
        *(bf16x8*)(Vt + r0 * 72 + o0) = vreg0;
        *(bf16x8*)(Vt + r1 * 72 + o1) = vreg1;
        const int kn = (kt + 1 < ntiles ? kt + 1 : kt) << 6;
        kreg0 = *(const bf16x8*)(Kg + (size_t)(kn + r0) * 64 + o0);
        kreg1 = *(const bf16x8*)(Kg + (size_t)(kn + r1) * 64 + o1);
        vreg0 = *(const bf16x8*)(Vg + (size_t)r0 * 2048 + kn + o0);
        vreg1 = *(const bf16x8*)(Vg + (size_t)r1 * 2048 + kn + o1);
        __syncthreads();

        if (kt < mytiles) {
            // ---- scores: C init = rel' (bf16 pre-scaled), MFMA adds scaled QK^T ----
            f32x4 s[2][4];
#pragma unroll
            for (int mt = 0; mt < 2; ++mt)
#pragma unroll
                for (int nt = 0; nt < 4; ++nt)
#pragma unroll
                    for (int g = 0; g < 4; ++g)
                        s[mt][nt][g] = b2f(relB[(size_t)(q0w + mt * 16 + quad * 4 + g) * SEQ
                                                + k0 + nt * 16 + l16]);
#pragma unroll
            for (int nt = 0; nt < 4; ++nt) {
                bf16x8 kb0 = *(const bf16x8*)(Ks + (nt * 16 + l16) * 72 + quad * 8);
                bf16x8 kb1 = *(const bf16x8*)(Ks + (nt * 16 + l16) * 72 + 32 + quad * 8);
#pragma unroll
                for (int mt = 0; mt < 2; ++mt) {
                    s[mt][nt] = __builtin_amdgcn_mfma_f32_16x16x32_bf16(qa[mt][0], kb0, s[mt][nt], 0, 0, 0);
                    s[mt][nt] = __builtin_amdgcn_mfma_f32_16x16x32_bf16(qa[mt][1], kb1, s[mt][nt], 0, 0, 0);
                }
            }
            // ---- causal mask (diagonal tile only) ----
            if (kt == mytiles - 1) {
#pragma unroll
                for (int mt = 0; mt < 2; ++mt)
#pragma unroll
                    for (int nt = 0; nt < 4; ++nt)
#pragma unroll
                        for (int g = 0; g < 4; ++g) {
                            const int q = q0w + mt * 16 + quad * 4 + g;
                            const int k = k0 + nt * 16 + l16;
                            if (k > q) s[mt][nt][g] = -1e30f;
                        }
            }
            // ---- online softmax (exp2 domain) ----
#pragma unroll
            for (int mt = 0; mt < 2; ++mt) {
                f32x4 t;
#pragma unroll
                for (int g = 0; g < 4; ++g)
                    t[g] = fmaxf(fmaxf(s[mt][0][g], s[mt][1][g]), fmaxf(s[mt][2][g], s[mt][3][g]));
#pragma unroll
                for (int off = 1; off < 16; off <<= 1)
#pragma unroll
                    for (int g = 0; g < 4; ++g)
                        t[g] = fmaxf(t[g], __shfl_xor(t[g], off, 64));
                f32x4 mn, alpha;
#pragma unroll
                for (int g = 0; g < 4; ++g) {
                    mn[g] = fmaxf(mrow[mt][g], t[g]);
                    alpha[g] = __builtin_amdgcn_exp2f(mrow[mt][g] - mn[g]);
                }
                mrow[mt] = mn;
#pragma unroll
                for (int g = 0; g < 4; ++g) lrow[mt][g] *= alpha[g];
#pragma unroll
                for (int dt = 0; dt < 4; ++dt)
#pragma unroll
                    for (int g = 0; g < 4; ++g) o[mt][dt][g] *= alpha[g];
#pragma unroll
                for (int nt = 0; nt < 4; ++nt)
#pragma unroll
                    for (int g = 0; g < 4; ++g)
                        s[mt][nt][g] = __builtin_amdgcn_exp2f(s[mt][nt][g] - mn[g]);
                f32x4 rs;
#pragma unroll
                for (int g = 0; g < 4; ++g)
                    rs[g] = (s[mt][0][g] + s[mt][1][g]) + (s[mt][2][g] + s[mt][3][g]);
#pragma unroll
                for (int off = 1; off < 16; off <<= 1)
#pragma unroll
                    for (int g = 0; g < 4; ++g)
                        rs[g] += __shfl_xor(rs[g], off, 64);
#pragma unroll
                for (int g = 0; g < 4; ++g) lrow[mt][g] += rs[g];
            }
            // ---- P -> bf16 -> per-wave LDS ----
#pragma unroll
            for (int mt = 0; mt < 2; ++mt)
#pragma unroll
                for (int nt = 0; nt < 4; ++nt)
#pragma unroll
                    for (int g = 0; g < 4; ++g)
                        Pl[(mt * 16 + quad * 4 + g) * 72 + nt * 16 + l16] = f2b(s[mt][nt][g]);
            // ---- PV ----
            bf16x8 pa[2][2];
#pragma unroll
            for (int mt = 0; mt < 2; ++mt)
#pragma unroll
                for (int ks = 0; ks < 2; ++ks)
                    pa[mt][ks] = *(const bf16x8*)(Pl + (mt * 16 + l16) * 72 + ks * 32 + quad * 8);
#pragma unroll
            for (int dt = 0; dt < 4; ++dt) {
                bf16x8 vb0 = *(const bf16x8*)(Vt + (dt * 16 + l16) * 72 + quad * 8);
                bf16x8 vb1 = *(const bf16x8*)(Vt + (dt * 16 + l16) * 72 + 32 + quad * 8);
#pragma unroll
                for (int mt = 0; mt < 2; ++mt) {
                    o[mt][dt] = __builtin_amdgcn_mfma_f32_16x16x32_bf16(pa[mt][0], vb0, o[mt][dt], 0, 0, 0);
                    o[mt][dt] = __builtin_amdgcn_mfma_f32_16x16x32_bf16(pa[mt][1], vb1, o[mt][dt], 0, 0, 0);
                }
            }
        }
        __syncthreads();
    }

    // ---- epilogue: O/l -> per-wave LDS -> coalesced stores ----
#pragma unroll
    for (int mt = 0; mt < 2; ++mt) {
        f32x4 linv;
#pragma unroll
        for (int g = 0; g < 4; ++g) linv[g] = 1.0f / lrow[mt][g];
#pragma unroll
        for (int dt = 0; dt < 4; ++dt)
#pragma unroll
            for (int g = 0; g < 4; ++g)
                Pl[(mt * 16 + quad * 4 + g) * 72 + dt * 16 + l16] = f2b(o[mt][dt][g] * linv[g]);
    }
#pragma unroll
    for (int p = 0; p < 4; ++p) {
        const int c = lane + p * 64;
        const int row = c >> 3, col = (c & 7) << 3;
        bf16x8 t = *(const bf16x8*)(Pl + row * 72 + col);
        *(bf16x8*)(Ob + ((size_t)b * SEQ + q0w + row) * HID + h * DH + col) = t;
    }
}

// ---------------- Output projection: out = O @ Wout^T + bout (fp32 out) ----------------
__global__ __launch_bounds__(256) void out_proj_kernel(
    const u16* __restrict__ X, const float* __restrict__ W,
    const float* __restrict__ bias, float* __restrict__ out)
{
    const int wid  = (blockIdx.x << 2) | (threadIdx.x >> 6);
    const int lane = threadIdx.x & 63;
    const int tm = wid >> 4;
    const int tn = wid & 15;
    const int n0 = tn << 6;
    const int m0 = tm << 6;

    const int quad = lane >> 4;
    const int l16  = lane & 15;

    f32x4 acc[4][4];
    const f32x4 zero = {0.f, 0.f, 0.f, 0.f};
#pragma unroll
    for (int r = 0; r < 4; ++r)
#pragma unroll
        for (int c = 0; c < 4; ++c) acc[r][c] = zero;

    const u16* ar[4]; const float* br[4];
#pragma unroll
    for (int r = 0; r < 4; ++r) ar[r] = X + (size_t)(m0 + r * 16 + l16) * 1024 + quad * 8;
#pragma unroll
    for (int c = 0; c < 4; ++c) br[c] = W + (size_t)(n0 + c * 16 + l16) * 1024 + quad * 8;

    for (int k0 = 0; k0 < 1024; k0 += 32) {
        bf16x8 a[4], b[4];
#pragma unroll
        for (int r = 0; r < 4; ++r) a[r] = *(const bf16x8*)(ar[r] + k0);
#pragma unroll
        for (int c = 0; c < 4; ++c) b[c] = cvt8(br[c] + k0);
#pragma unroll
        for (int r = 0; r < 4; ++r)
#pragma unroll
            for (int c = 0; c < 4; ++c)
                acc[r][c] = __builtin_amdgcn_mfma_f32_16x16x32_bf16(a[r], b[c], acc[r][c], 0, 0, 0);
    }

#pragma unroll
    for (int c = 0; c < 4; ++c) {
        const int n = n0 + c * 16 + l16;
        const float bn = bias[n];
#pragma unroll
        for (int r = 0; r < 4; ++r) {
#pragma unroll
            for (int g = 0; g < 4; ++g) {
                const int m = m0 + r * 16 + quad * 4 + g;
                out[(size_t)m * 1024 + n] = acc[r][c][g] + bn;
            }
        }
    }
}

extern "C" void kernel_launch(void* const* d_in, const int* in_sizes, int n_in,
                              void* d_out, int out_size, void* d_ws, size_t ws_size,
                              hipStream_t stream)
{
    const float* q   = (const float*)d_in[0];
    const float* k   = (const float*)d_in[1];
    const float* v   = (const float*)d_in[2];
    const float* rel = (const float*)d_in[3];
    // d_in[4] = attn_mask: statically causal tril, not read
    const float* wq = (const float*)d_in[5];  const float* bq = (const float*)d_in[6];
    const float* wk = (const float*)d_in[7];  const float* bk = (const float*)d_in[8];
    const float* wv = (const float*)d_in[9];  const float* bv = (const float*)d_in[10];
    const float* wo = (const float*)d_in[11]; const float* bo = (const float*)d_in[12];

    u16* ws = (u16*)d_ws;                 // 96 MB used
    u16* Qw   = ws;
    u16* Kw   = ws + 8388608ULL;
    u16* Vw   = ws + 16777216ULL;
    u16* Ow   = ws + 25165824ULL;
    u16* relb = ws + 33554432ULL;

    rel_cvt_kernel<<<1024, 256, 0, stream>>>(rel, relb);
    qkv_proj_kernel<<<1536, 256, 0, stream>>>(q, k, v, wq, bq, wk, bk, wv, bv, Qw, Kw, Vw);
    attn_kernel<<<1024, 256, 0, stream>>>(Qw, Kw, Vw, relb, Ow);
    out_proj_kernel<<<512, 256, 0, stream>>>(Ow, wo, bo, (float*)d_out);
}